// Round 4
// baseline (224.183 us; speedup 1.0000x reference)
//
#include <hip/hip_runtime.h>
#include <math.h>

constexpr int K = 512;
constexpr int D = 64;
constexpr int HW = 64 * 64;                      // 4096
constexpr int NPIX = 131072;
constexpr long long NELEM = (long long)NPIX * D; // 8388608
constexpr float BETA = 0.25f;
constexpr int PPB = 64;                          // pixels per block
constexpr int NBLK = NPIX / PPB;                 // 2048 blocks (8 per CU queued)

typedef __attribute__((ext_vector_type(8))) short short8;
typedef __attribute__((ext_vector_type(4))) float f32x4;

union frag_u { uint4 u; short8 s; };

__device__ inline unsigned short bf16rne(float x) {
    unsigned u = __float_as_uint(x);
    unsigned r = (u + 0x7FFFu + ((u >> 16) & 1u)) >> 16;
    return (unsigned short)r;
}

// truncated-bf16 pack: f0 -> low ushort, f1 -> high ushort (one v_perm_b32)
__device__ inline unsigned pk(float f0, float f1) {
    return __builtin_amdgcn_perm(__float_as_uint(f1), __float_as_uint(f0), 0x07060302u);
}

// ---- Prep: build bf16 B-frags (-2*E) + packed ||e||^2 hi/lo into workspace.
// Exact same arithmetic/order as the verified round-1 in-kernel B build.
__global__ void vq_prep(const float* __restrict__ E,
                        uint4* __restrict__ gsb, unsigned* __restrict__ eepk) {
    const int n = blockIdx.x * 128 + threadIdx.x;   // 0..511
    const float4* er = (const float4*)(E + (size_t)n * D);
    const int tile = n >> 4, col = n & 15;
    float acc = 0.f;
#pragma unroll
    for (int g = 0; g < 8; ++g) {
        float4 c0 = er[2 * g], c1 = er[2 * g + 1];
        acc = fmaf(c0.x, c0.x, acc); acc = fmaf(c0.y, c0.y, acc);
        acc = fmaf(c0.z, c0.z, acc); acc = fmaf(c0.w, c0.w, acc);
        acc = fmaf(c1.x, c1.x, acc); acc = fmaf(c1.y, c1.y, acc);
        acc = fmaf(c1.z, c1.z, acc); acc = fmaf(c1.w, c1.w, acc);
        uint4 w;
        w.x = pk(-2.f * c0.x, -2.f * c0.y);
        w.y = pk(-2.f * c0.z, -2.f * c0.w);
        w.z = pk(-2.f * c1.x, -2.f * c1.y);
        w.w = pk(-2.f * c1.z, -2.f * c1.w);
        gsb[(tile * 2 + (g >> 2)) * 64 + ((g & 3) * 16 + col)] = w;
    }
    unsigned short eh = bf16rne(acc);
    unsigned short el = bf16rne(acc - __uint_as_float((unsigned)eh << 16));
    eepk[n] = (unsigned)eh | ((unsigned)el << 16);
}

// ---- Main: 256 threads / 4 waves, PPB=64. Each wave owns 128 codes in
// REGISTERS (loaded once, coalesced). A-tiles in 8 KB LDS. Main loop is pure
// reg-MFMA + LDS reads: no global access, no per-iter latency. Cross-wave
// argmin via per-wave LDS keys + fminf (verified round-1 numerics throughout).
__global__ __launch_bounds__(256, 4) void vq_main(
    const float* __restrict__ z, const float* __restrict__ E,
    float* __restrict__ out, int out_size,
    const uint4* __restrict__ gsb, const unsigned* __restrict__ eepk,
    float* __restrict__ sse_arr, unsigned int* __restrict__ counts,
    unsigned int* __restrict__ ticket) {

    __shared__ __align__(16) uint4 sa[8 * 64];   // 4 tiles x 2 halves x 64 lanes = 8 KB
    __shared__ float wkeys[4][PPB];              // per-wave best key per pixel
    __shared__ int bks[PPB];
    __shared__ unsigned int hcnt[K];
    __shared__ float zqs[4];
    __shared__ float red[4], red2[4];
    __shared__ int sflag;

    const int tid = threadIdx.x;
    const int wave = tid >> 6;      // 0..3
    const int lane = tid & 63;
    const int quad = lane >> 4;     // k-group
    const int lx = lane & 15;       // m for A, n for B, col for C/D

    const int p0 = blockIdx.x * PPB;
    const int b = p0 >> 12;
    const int s0 = p0 & (HW - 1);

    hcnt[tid] = 0u;
    hcnt[tid + 256] = 0u;

    // ---- A loads: wave w stages tile w (pixels w*16..w*16+15), 16 dwords ----
    const float* zb = z + (size_t)b * (D * HW) + s0 + wave * 16;
    float z0[16];
#pragma unroll
    for (int c = 0; c < 2; ++c)
#pragma unroll
        for (int j = 0; j < 8; ++j)
            z0[c * 8 + j] = zb[(size_t)(c * 32 + quad * 8 + j) * HW + lx];

    // ---- pack to bf16 frags -> LDS; fp32 ||z||^2 partial ----
    {
        float zq2 = 0.f;
#pragma unroll
        for (int i = 0; i < 16; ++i) zq2 = fmaf(z0[i], z0[i], zq2);
        frag_u a0, a1;
        a0.u.x = pk(z0[0], z0[1]);   a0.u.y = pk(z0[2], z0[3]);
        a0.u.z = pk(z0[4], z0[5]);   a0.u.w = pk(z0[6], z0[7]);
        a1.u.x = pk(z0[8], z0[9]);   a1.u.y = pk(z0[10], z0[11]);
        a1.u.z = pk(z0[12], z0[13]); a1.u.w = pk(z0[14], z0[15]);
        sa[(wave * 2 + 0) * 64 + lane] = a0.u;
        sa[(wave * 2 + 1) * 64 + lane] = a1.u;
        // block ||z||^2 only needs the SUM, not per-pixel attribution
#pragma unroll
        for (int off = 32; off > 0; off >>= 1) zq2 += __shfl_down(zq2, off, 64);
        if (lane == 0) zqs[wave] = zq2;
    }

    // ---- B frags: this wave's 128 codes, loaded ONCE, coalesced from L2 ----
    frag_u bf[8][2];
    unsigned bee[8];
#pragma unroll
    for (int ct = 0; ct < 8; ++ct) {
        const int ct2 = wave * 8 + ct;
        bf[ct][0].u = gsb[(ct2 * 2 + 0) * 64 + lane];
        bf[ct][1].u = gsb[(ct2 * 2 + 1) * 64 + lane];
        bee[ct] = eepk[ct2 * 16 + lx];
    }

    frag_u aee;
    aee.u.x = (quad == 0) ? 0x3F803F80u : 0u;
    aee.u.y = 0u; aee.u.z = 0u; aee.u.w = 0u;

    __syncthreads();   // sa + zqs resident

    // ---- Main loop: 4 A-tiles x 8 reg col-tiles; pure reg/LDS, no global ----
#pragma unroll 1
    for (int t = 0; t < 4; ++t) {
        frag_u A0, A1;
        A0.u = sa[(t * 2 + 0) * 64 + lane];
        A1.u = sa[(t * 2 + 1) * 64 + lane];
        float best4[4];
#pragma unroll
        for (int r = 0; r < 4; ++r) best4[r] = __uint_as_float(0x7F800000u);
#pragma unroll
        for (int ct = 0; ct < 8; ++ct) {
            frag_u beef;
            beef.u.x = (quad == 0) ? bee[ct] : 0u;
            beef.u.y = 0u; beef.u.z = 0u; beef.u.w = 0u;
            f32x4 acc = {0.f, 0.f, 0.f, 0.f};
            acc = __builtin_amdgcn_mfma_f32_16x16x32_bf16(A0.s, bf[ct][0].s, acc, 0, 0, 0);
            acc = __builtin_amdgcn_mfma_f32_16x16x32_bf16(A1.s, bf[ct][1].s, acc, 0, 0, 0);
            acc = __builtin_amdgcn_mfma_f32_16x16x32_bf16(aee.s, beef.s, acc, 0, 0, 0);
            unsigned col = (unsigned)(wave * 128 + ct * 16 + lx);
#pragma unroll
            for (int r = 0; r < 4; ++r) {
                float kk = __uint_as_float((__float_as_uint(acc[r]) & 0xFFFFFE00u) | col);
                best4[r] = fminf(best4[r], kk);
            }
        }
        // butterfly min over the 16 code-columns; one writer per pixel row
#pragma unroll
        for (int r = 0; r < 4; ++r) {
            float v = best4[r];
#pragma unroll
            for (int m = 1; m < 16; m <<= 1) v = fminf(v, __shfl_xor(v, m, 64));
            if (lx == 4 * quad + r)
                wkeys[wave][t * 16 + 4 * quad + r] = v;
        }
    }

    __syncthreads();   // all wave keys written

    // ---- Combine across waves (wave 0): decode winner, hist, dist-sum ----
    float dsum = 0.f;
    if (tid < PPB) {
        float v = fminf(fminf(wkeys[0][tid], wkeys[1][tid]),
                        fminf(wkeys[2][tid], wkeys[3][tid]));
        unsigned u = __float_as_uint(v);
        int c = (int)(u & 0x1FFu);
        bks[tid] = c;
        atomicAdd(&hcnt[c], 1u);
        dsum = __uint_as_float(u & 0xFFFFFE00u);
    }
#pragma unroll
    for (int off = 32; off > 0; off >>= 1) dsum += __shfl_down(dsum, off, 64);

    __syncthreads();   // bks + hcnt combine done

    if (tid == 0)
        sse_arr[blockIdx.x] = dsum + zqs[0] + zqs[1] + zqs[2] + zqs[3];

    // ---- Epilogue: thread -> (pixel = tid&63, d-quarter = tid>>6) ----
    {
        int p = tid & (PPB - 1);
        int dq = tid >> 6;          // 0..3
        int bk = bks[p];
        const float4* Er = (const float4*)(E + (size_t)bk * D + dq * 16);
        float* ob = out + 1 + (size_t)b * (D * HW) + (size_t)dq * 16 * HW + s0 + p;
#pragma unroll
        for (int v4i = 0; v4i < 4; ++v4i) {
            float4 e4 = Er[v4i];
            ob[(size_t)(4 * v4i + 0) * HW] = e4.x;
            ob[(size_t)(4 * v4i + 1) * HW] = e4.y;
            ob[(size_t)(4 * v4i + 2) * HW] = e4.z;
            ob[(size_t)(4 * v4i + 3) * HW] = e4.w;
        }
    }

    // ---- flush histogram (<=64 nonzero bins per block) ----
    {
        unsigned hc0 = hcnt[tid];
        if (hc0) atomicAdd(&counts[tid], hc0);
        unsigned hc1 = hcnt[tid + 256];
        if (hc1) atomicAdd(&counts[tid + 256], hc1);
    }

    // ---- fused finalize: last block computes loss + perplexity ----
    __syncthreads();
    if (tid == 0) {
        __threadfence();
        unsigned t = atomicAdd(ticket, 1u);
        sflag = (t == (unsigned)(NBLK - 1)) ? 1 : 0;
    }
    __syncthreads();
    if (sflag) {
        float t = 0.f, s = 0.f;
#pragma unroll
        for (int i = 0; i < 2; ++i) {
            float cf = (float)atomicAdd(&counts[tid + 256 * i], 0u);
            float pa = cf / (float)NPIX + 1e-10f;
            t += pa * logf(pa);
        }
#pragma unroll
        for (int i = 0; i < 8; ++i)
            s += atomicAdd(&sse_arr[tid + 256 * i], 0.0f);
#pragma unroll
        for (int off = 32; off > 0; off >>= 1) {
            t += __shfl_down(t, off, 64);
            s += __shfl_down(s, off, 64);
        }
        if (lane == 0) { red[wave] = t; red2[wave] = s; }
        __syncthreads();
        if (tid == 0) {
            float tot = 0.f, st = 0.f;
#pragma unroll
            for (int i = 0; i < 4; ++i) { tot += red[i]; st += red2[i]; }
            out[0] = (1.f + BETA) * st / (float)NELEM;
            out[out_size - 1] = expf(-tot);
        }
    }
}

extern "C" void kernel_launch(void* const* d_in, const int* in_sizes, int n_in,
                              void* d_out, int out_size, void* d_ws, size_t ws_size,
                              hipStream_t stream) {
    const float* z = (const float*)d_in[0];
    const float* E = (const float*)d_in[1];
    float* out = (float*)d_out;

    unsigned int* base = (unsigned int*)d_ws;
    unsigned int* ticket = base;                         // [0..3]
    unsigned int* counts = base + 4;                     // 512 uints
    float* sse_arr = (float*)(base + 4 + K);             // 2048 floats (per block)
    uint4* gsb = (uint4*)(base + 4 + K + NBLK);          // 64 KB B-frags (16-B aligned)
    unsigned int* eepk = base + 4 + K + NBLK + 4096 * 4; // 512 uints

    hipMemsetAsync(d_ws, 0, (4 + K) * sizeof(unsigned int), stream);  // ticket + counts
    vq_prep<<<4, 128, 0, stream>>>(E, gsb, eepk);
    vq_main<<<NBLK, 256, 0, stream>>>(z, E, out, out_size, gsb, eepk,
                                      sse_arr, counts, ticket);
}

// Round 5
// 147.756 us; speedup vs baseline: 1.5172x; 1.5172x over previous
//
#include <hip/hip_runtime.h>
#include <math.h>

constexpr int K = 512;
constexpr int D = 64;
constexpr int HW = 64 * 64;                      // 4096
constexpr int NPIX = 131072;
constexpr long long NELEM = (long long)NPIX * D; // 8388608
constexpr float BETA = 0.25f;
constexpr int PPB = 128;                         // pixels per block
constexpr int NBLK = NPIX / PPB;                 // 1024 blocks (2 resident + 2 queued / CU)

typedef __attribute__((ext_vector_type(8))) short short8;
typedef __attribute__((ext_vector_type(4))) float f32x4;

union frag_u { uint4 u; short8 s; };

__device__ inline unsigned short bf16rne(float x) {
    unsigned u = __float_as_uint(x);
    unsigned r = (u + 0x7FFFu + ((u >> 16) & 1u)) >> 16;
    return (unsigned short)r;
}

// truncated-bf16 pack: f0 -> low ushort, f1 -> high ushort (one v_perm_b32)
__device__ inline unsigned pk(float f0, float f1) {
    return __builtin_amdgcn_perm(__float_as_uint(f1), __float_as_uint(f0), 0x07060302u);
}

// ---- Prep: build bf16 B-frags (-2*E) + packed ||e||^2 hi/lo into workspace.
// (verified identical outputs in R3/R4 runs)
__global__ void vq_prep(const float* __restrict__ E,
                        uint4* __restrict__ gsb, unsigned* __restrict__ eepk) {
    const int n = blockIdx.x * 128 + threadIdx.x;   // 0..511
    const float4* er = (const float4*)(E + (size_t)n * D);
    const int tile = n >> 4, col = n & 15;
    float acc = 0.f;
#pragma unroll
    for (int g = 0; g < 8; ++g) {
        float4 c0 = er[2 * g], c1 = er[2 * g + 1];
        acc = fmaf(c0.x, c0.x, acc); acc = fmaf(c0.y, c0.y, acc);
        acc = fmaf(c0.z, c0.z, acc); acc = fmaf(c0.w, c0.w, acc);
        acc = fmaf(c1.x, c1.x, acc); acc = fmaf(c1.y, c1.y, acc);
        acc = fmaf(c1.z, c1.z, acc); acc = fmaf(c1.w, c1.w, acc);
        uint4 w;
        w.x = pk(-2.f * c0.x, -2.f * c0.y);
        w.y = pk(-2.f * c0.z, -2.f * c0.w);
        w.z = pk(-2.f * c1.x, -2.f * c1.y);
        w.w = pk(-2.f * c1.z, -2.f * c1.w);
        gsb[(tile * 2 + (g >> 2)) * 64 + ((g & 3) * 16 + col)] = w;
    }
    unsigned short eh = bf16rne(acc);
    unsigned short el = bf16rne(acc - __uint_as_float((unsigned)eh << 16));
    eepk[n] = (unsigned)eh | ((unsigned)el << 16);
}

// ---- Main: R1's verified LDS-B loop, but B arrives via global_load_lds DMA
// (no E read, no build VALU, no VGPR round-trip) issued before the z phase.
// PPB=128 -> 1024 blocks: retirement-staggered cross-block phase overlap.
__global__ __launch_bounds__(512, 4) void vq_main(
    const float* __restrict__ z, const float* __restrict__ E,
    float* __restrict__ out, int out_size,
    const uint4* __restrict__ gsb, const unsigned* __restrict__ eepk,
    float* __restrict__ sse_arr, unsigned int* __restrict__ counts,
    unsigned int* __restrict__ ticket) {

    __shared__ __align__(16) unsigned short sb[32768];   // 64 KB B-frags
    __shared__ __align__(16) unsigned int eelds[K];      // 2 KB packed ||e||^2
    __shared__ int bks[PPB];
    __shared__ unsigned int hcnt[K];
    __shared__ float red[8], red2[8];
    __shared__ int sflag;

    const int tid = threadIdx.x;
    const int wave = tid >> 6;      // 0..7
    const int lane = tid & 63;
    const int quad = lane >> 4;     // k-group
    const int lx = lane & 15;       // m for A, n for B, col for C/D

    const int p0 = blockIdx.x * PPB;
    const int b = p0 >> 12;
    const int s0 = p0 & (HW - 1);

    hcnt[tid] = 0u;

    // ---- B + eepk DMA straight to LDS (async, zero VGPR), issued FIRST ----
    {
        const char* gs = (const char*)gsb + wave * 8192 + lane * 16;
        char* ls = (char*)sb + wave * 8192;             // wave-uniform base
#pragma unroll
        for (int i = 0; i < 8; ++i)
            __builtin_amdgcn_global_load_lds(
                (const __attribute__((address_space(1))) void*)(gs + i * 1024),
                (__attribute__((address_space(3))) void*)(ls + i * 1024), 16, 0, 0);
        __builtin_amdgcn_global_load_lds(
            (const __attribute__((address_space(1))) void*)(eepk + wave * 64 + lane),
            (__attribute__((address_space(3))) void*)((char*)eelds + wave * 256), 4, 0, 0);
    }

    // ---- A loads: wave w = pixels w*16..w*16+15; 16 scattered dwords ----
    const float* zb = z + (size_t)b * (D * HW) + s0 + wave * 16;
    float z0[16];
#pragma unroll
    for (int c = 0; c < 2; ++c)
#pragma unroll
        for (int j = 0; j < 8; ++j)
            z0[c * 8 + j] = zb[(size_t)(c * 32 + quad * 8 + j) * HW + lx];

    // ---- A pack + exact fp32 ||z||^2 ----
    frag_u a[2];
    float zsq = 0.f;
#pragma unroll
    for (int i = 0; i < 16; ++i) zsq = fmaf(z0[i], z0[i], zsq);
    a[0].u.x = pk(z0[0], z0[1]);   a[0].u.y = pk(z0[2], z0[3]);
    a[0].u.z = pk(z0[4], z0[5]);   a[0].u.w = pk(z0[6], z0[7]);
    a[1].u.x = pk(z0[8], z0[9]);   a[1].u.y = pk(z0[10], z0[11]);
    a[1].u.z = pk(z0[12], z0[13]); a[1].u.w = pk(z0[14], z0[15]);

    // ee fold-in A operand: k slots 0,1 = 1.0 (quad 0 only)
    frag_u aee;
    aee.u.x = (quad == 0) ? 0x3F803F80u : 0u;
    aee.u.y = 0u; aee.u.z = 0u; aee.u.w = 0u;

    float best0[4];
#pragma unroll
    for (int r = 0; r < 4; ++r) best0[r] = __uint_as_float(0x7F800000u);

    __syncthreads();   // drains DMA (vmcnt) + hcnt init; barrier-free main loop

    // ---- Main loop: 16 x 2 col-tiles (R1-identical layout/numerics) ----
#pragma unroll 1
    for (int t2 = 0; t2 < 16; ++t2) {
        const int ta = 2 * t2, tb = 2 * t2 + 1;
        frag_u ba0, ba1, bb0, bb1;
        ba0.u = *(const uint4*)&sb[(ta * 2 + 0) * 512 + lane * 8];
        ba1.u = *(const uint4*)&sb[(ta * 2 + 1) * 512 + lane * 8];
        bb0.u = *(const uint4*)&sb[(tb * 2 + 0) * 512 + lane * 8];
        bb1.u = *(const uint4*)&sb[(tb * 2 + 1) * 512 + lane * 8];
        frag_u beea, beeb;
        beea.u.x = (quad == 0) ? eelds[ta * 16 + lx] : 0u;
        beea.u.y = 0u; beea.u.z = 0u; beea.u.w = 0u;
        beeb.u.x = (quad == 0) ? eelds[tb * 16 + lx] : 0u;
        beeb.u.y = 0u; beeb.u.z = 0u; beeb.u.w = 0u;

        f32x4 aa0 = {0,0,0,0}, ab0 = {0,0,0,0};
        aa0 = __builtin_amdgcn_mfma_f32_16x16x32_bf16(a[0].s, ba0.s, aa0, 0, 0, 0);
        ab0 = __builtin_amdgcn_mfma_f32_16x16x32_bf16(a[0].s, bb0.s, ab0, 0, 0, 0);
        aa0 = __builtin_amdgcn_mfma_f32_16x16x32_bf16(a[1].s, ba1.s, aa0, 0, 0, 0);
        ab0 = __builtin_amdgcn_mfma_f32_16x16x32_bf16(a[1].s, bb1.s, ab0, 0, 0, 0);
        aa0 = __builtin_amdgcn_mfma_f32_16x16x32_bf16(aee.s, beea.s, aa0, 0, 0, 0);
        ab0 = __builtin_amdgcn_mfma_f32_16x16x32_bf16(aee.s, beeb.s, ab0, 0, 0, 0);

        unsigned cba = (unsigned)(ta * 16 + lx), cbb = (unsigned)(tb * 16 + lx);
#pragma unroll
        for (int r = 0; r < 4; ++r) {
            float ka0 = __uint_as_float((__float_as_uint(aa0[r]) & 0xFFFFFE00u) | cba);
            float kb0 = __uint_as_float((__float_as_uint(ab0[r]) & 0xFFFFFE00u) | cbb);
            best0[r] = fminf(fminf(best0[r], ka0), kb0);
        }
    }

    // ---- Cross-lane argmin (butterfly over low 4 lane bits) + SSE ----
    float lsse = zsq;
#pragma unroll
    for (int r = 0; r < 4; ++r) {
        float v = best0[r];
#pragma unroll
        for (int m = 1; m < 16; m <<= 1) v = fminf(v, __shfl_xor(v, m, 64));
        if (lx == 4 * quad + r) {   // one writer per (quad,r): row = 4*quad+r
            unsigned u = __float_as_uint(v);
            int c = (int)(u & 0x1FFu);
            bks[wave * 16 + 4 * quad + r] = c;
            atomicAdd(&hcnt[c], 1u);
            lsse += __uint_as_float(u & 0xFFFFFE00u);
        }
    }
#pragma unroll
    for (int off = 32; off > 0; off >>= 1) lsse += __shfl_down(lsse, off, 64);
    if (lane == 0) red[wave] = lsse;

    __syncthreads();   // bks + red + hcnt visible
    if (tid == 0) {
        float s = 0.f;
#pragma unroll
        for (int i = 0; i < 8; ++i) s += red[i];
        sse_arr[blockIdx.x] = s;
    }

    // ---- Epilogue: thread -> (pixel = tid&127, d-quarter = tid>>7) ----
    {
        int q = tid & (PPB - 1);
        int dq = tid >> 7;          // 0..3
        int bk = bks[q];
        const float4* Er = (const float4*)(E + (size_t)bk * D + dq * 16);
        float* ob = out + 1 + (size_t)b * (D * HW) + (size_t)dq * 16 * HW + s0 + q;
#pragma unroll
        for (int v4i = 0; v4i < 4; ++v4i) {
            float4 e4 = Er[v4i];
            ob[(size_t)(4 * v4i + 0) * HW] = e4.x;
            ob[(size_t)(4 * v4i + 1) * HW] = e4.y;
            ob[(size_t)(4 * v4i + 2) * HW] = e4.z;
            ob[(size_t)(4 * v4i + 3) * HW] = e4.w;
        }
    }

    // ---- flush histogram ----
    {
        unsigned hc = hcnt[tid];
        if (hc) atomicAdd(&counts[tid], hc);
    }

    // ---- fused finalize: last block computes loss + perplexity ----
    __syncthreads();
    if (tid == 0) {
        __threadfence();
        unsigned t = atomicAdd(ticket, 1u);
        sflag = (t == (unsigned)(NBLK - 1)) ? 1 : 0;
    }
    __syncthreads();
    if (sflag) {
        float cf = (float)atomicAdd(&counts[tid], 0u);
        float pa = cf / (float)NPIX + 1e-10f;
        float t = pa * logf(pa);
        float s = atomicAdd(&sse_arr[tid], 0.0f) + atomicAdd(&sse_arr[tid + 512], 0.0f);
#pragma unroll
        for (int off = 32; off > 0; off >>= 1) {
            t += __shfl_down(t, off, 64);
            s += __shfl_down(s, off, 64);
        }
        if (lane == 0) { red[wave] = t; red2[wave] = s; }
        __syncthreads();
        if (tid == 0) {
            float tot = 0.f, st = 0.f;
#pragma unroll
            for (int i = 0; i < 8; ++i) { tot += red[i]; st += red2[i]; }
            out[0] = (1.f + BETA) * st / (float)NELEM;
            out[out_size - 1] = expf(-tot);
        }
    }
}

extern "C" void kernel_launch(void* const* d_in, const int* in_sizes, int n_in,
                              void* d_out, int out_size, void* d_ws, size_t ws_size,
                              hipStream_t stream) {
    const float* z = (const float*)d_in[0];
    const float* E = (const float*)d_in[1];
    float* out = (float*)d_out;

    unsigned int* base = (unsigned int*)d_ws;
    unsigned int* ticket = base;                          // [0..3]
    unsigned int* counts = base + 4;                      // 512 uints
    float* sse_arr = (float*)(base + 4 + K);              // 1024 floats (per block)
    uint4* gsb = (uint4*)(base + 4 + K + NBLK);           // 64 KB B-frags (16-B aligned)
    unsigned int* eepk = base + 4 + K + NBLK + 4096 * 4;  // 512 uints

    hipMemsetAsync(d_ws, 0, (4 + K) * sizeof(unsigned int), stream);  // ticket + counts
    vq_prep<<<4, 128, 0, stream>>>(E, gsb, eepk);
    vq_main<<<NBLK, 512, 0, stream>>>(z, E, out, out_size, gsb, eepk,
                                      sse_arr, counts, ticket);
}

// Round 6
// 146.635 us; speedup vs baseline: 1.5288x; 1.0076x over previous
//
#include <hip/hip_runtime.h>
#include <math.h>

constexpr int K = 512;
constexpr int D = 64;
constexpr int HW = 64 * 64;                      // 4096
constexpr int NPIX = 131072;
constexpr long long NELEM = (long long)NPIX * D; // 8388608
constexpr float BETA = 0.25f;
constexpr int PPB = 128;                         // pixels per block
constexpr int NBLK = NPIX / PPB;                 // 1024 blocks (4 resident / CU)

typedef __attribute__((ext_vector_type(8))) short short8;
typedef __attribute__((ext_vector_type(4))) float f32x4;

union frag_u { uint4 u; short8 s; };

__device__ inline unsigned short bf16rne(float x) {
    unsigned u = __float_as_uint(x);
    unsigned r = (u + 0x7FFFu + ((u >> 16) & 1u)) >> 16;
    return (unsigned short)r;
}

// truncated-bf16 pack: f0 -> low ushort, f1 -> high ushort (one v_perm_b32)
__device__ inline unsigned pk(float f0, float f1) {
    return __builtin_amdgcn_perm(__float_as_uint(f1), __float_as_uint(f0), 0x07060302u);
}

// ---- Prep: build bf16 B-frags (-2*E) + packed ||e||^2 hi/lo into workspace.
// (verified identical outputs R3-R5)
__global__ void vq_prep(const float* __restrict__ E,
                        uint4* __restrict__ gsb, unsigned* __restrict__ eepk) {
    const int n = blockIdx.x * 128 + threadIdx.x;   // 0..511
    const float4* er = (const float4*)(E + (size_t)n * D);
    const int tile = n >> 4, col = n & 15;
    float acc = 0.f;
#pragma unroll
    for (int g = 0; g < 8; ++g) {
        float4 c0 = er[2 * g], c1 = er[2 * g + 1];
        acc = fmaf(c0.x, c0.x, acc); acc = fmaf(c0.y, c0.y, acc);
        acc = fmaf(c0.z, c0.z, acc); acc = fmaf(c0.w, c0.w, acc);
        acc = fmaf(c1.x, c1.x, acc); acc = fmaf(c1.y, c1.y, acc);
        acc = fmaf(c1.z, c1.z, acc); acc = fmaf(c1.w, c1.w, acc);
        uint4 w;
        w.x = pk(-2.f * c0.x, -2.f * c0.y);
        w.y = pk(-2.f * c0.z, -2.f * c0.w);
        w.z = pk(-2.f * c1.x, -2.f * c1.y);
        w.w = pk(-2.f * c1.z, -2.f * c1.w);
        gsb[(tile * 2 + (g >> 2)) * 64 + ((g & 3) * 16 + col)] = w;
    }
    unsigned short eh = bf16rne(acc);
    unsigned short el = bf16rne(acc - __uint_as_float((unsigned)eh << 16));
    eepk[n] = (unsigned)eh | ((unsigned)el << 16);
}

// ---- Main: B streamed through a 4-window x 4 KB LDS ring via global_load_lds
// (prefetch depth 2, counted vmcnt(2), raw s_barrier per iter). LDS ~21 KB ->
// 4 blocks/CU resident (32 waves = 100% of slots). Numerics = R1/R5 verified.
__global__ __launch_bounds__(512, 8) void vq_main(
    const float* __restrict__ z, const float* __restrict__ E,
    float* __restrict__ out, int out_size,
    const uint4* __restrict__ gsb, const unsigned* __restrict__ eepk,
    float* __restrict__ sse_arr, unsigned int* __restrict__ counts,
    unsigned int* __restrict__ ticket) {

    __shared__ __align__(16) unsigned short sb[8192];   // 4 windows x 4 KB
    __shared__ __align__(16) unsigned int eelds[K];     // 2 KB packed ||e||^2
    __shared__ int bks[PPB];
    __shared__ unsigned int hcnt[K];
    __shared__ float red[8], red2[8];
    __shared__ int sflag;

    const int tid = threadIdx.x;
    const int wave = tid >> 6;      // 0..7
    const int lane = tid & 63;
    const int quad = lane >> 4;     // k-group
    const int lx = lane & 15;       // m for A, n for B, col for C/D

    const int p0 = blockIdx.x * PPB;
    const int b = p0 >> 12;
    const int s0 = p0 & (HW - 1);

    hcnt[tid] = 0u;
    __syncthreads();   // free drain (no vmem outstanding); hcnt init visible

    // ---- Prologue DMA: windows 0,1 (waves 0-3) + eelds (all waves) ----
    if (wave < 4) {
#pragma unroll
        for (int wn = 0; wn < 2; ++wn)
            __builtin_amdgcn_global_load_lds(
                (const __attribute__((address_space(1))) void*)
                    ((const char*)gsb + (size_t)(4 * wn + wave) * 1024 + lane * 16),
                (__attribute__((address_space(3))) void*)
                    ((char*)sb + wn * 4096 + wave * 1024), 16, 0, 0);
    }
    __builtin_amdgcn_global_load_lds(
        (const __attribute__((address_space(1))) void*)(eepk + wave * 64 + lane),
        (__attribute__((address_space(3))) void*)((char*)eelds + wave * 256), 4, 0, 0);

    // ---- A loads: wave w = pixels w*16..w*16+15; 16 scattered dwords ----
    const float* zb = z + (size_t)b * (D * HW) + s0 + wave * 16;
    float z0[16];
#pragma unroll
    for (int c = 0; c < 2; ++c)
#pragma unroll
        for (int j = 0; j < 8; ++j)
            z0[c * 8 + j] = zb[(size_t)(c * 32 + quad * 8 + j) * HW + lx];

    // ---- A pack + exact fp32 ||z||^2 (auto-drains z loads; FIFO vmcnt =>
    //      eelds + win0/win1 DMAs, issued earlier, are also complete) ----
    frag_u a[2];
    float zsq = 0.f;
#pragma unroll
    for (int i = 0; i < 16; ++i) zsq = fmaf(z0[i], z0[i], zsq);
    a[0].u.x = pk(z0[0], z0[1]);   a[0].u.y = pk(z0[2], z0[3]);
    a[0].u.z = pk(z0[4], z0[5]);   a[0].u.w = pk(z0[6], z0[7]);
    a[1].u.x = pk(z0[8], z0[9]);   a[1].u.y = pk(z0[10], z0[11]);
    a[1].u.z = pk(z0[12], z0[13]); a[1].u.w = pk(z0[14], z0[15]);

    frag_u aee;
    aee.u.x = (quad == 0) ? 0x3F803F80u : 0u;
    aee.u.y = 0u; aee.u.z = 0u; aee.u.w = 0u;

    float best0[4];
#pragma unroll
    for (int r = 0; r < 4; ++r) best0[r] = __uint_as_float(0x7F800000u);

    // ---- Main loop: 16 iters; per iter {issue DMA(t+2); vmcnt(2); s_barrier;
    //      compute window t}. One raw barrier per iter; vmcnt never drained. ----
#pragma unroll 1
    for (int t2 = 0; t2 < 16; ++t2) {
        const int tn = (t2 + 2) & 15;   // wrap refetch at t2=14,15: benign
        if (wave < 4)
            __builtin_amdgcn_global_load_lds(
                (const __attribute__((address_space(1))) void*)
                    ((const char*)gsb + (size_t)(4 * tn + wave) * 1024 + lane * 16),
                (__attribute__((address_space(3))) void*)
                    ((char*)sb + (tn & 3) * 4096 + wave * 1024), 16, 0, 0);

        asm volatile("s_waitcnt vmcnt(2)" ::: "memory");  // window t landed (wave-local)
        __builtin_amdgcn_s_barrier();                     // ...and for ALL waves
        __builtin_amdgcn_sched_barrier(0);                // no hoisting of reads above

        const int bi = (t2 & 3) * 2048;   // ushort base of window t2
        frag_u ba0, ba1, bb0, bb1;
        ba0.u = *(const uint4*)&sb[bi + 0 * 512 + lane * 8];
        ba1.u = *(const uint4*)&sb[bi + 1 * 512 + lane * 8];
        bb0.u = *(const uint4*)&sb[bi + 2 * 512 + lane * 8];
        bb1.u = *(const uint4*)&sb[bi + 3 * 512 + lane * 8];
        const int ta = 2 * t2, tb = 2 * t2 + 1;
        frag_u beea, beeb;
        beea.u.x = (quad == 0) ? eelds[ta * 16 + lx] : 0u;
        beea.u.y = 0u; beea.u.z = 0u; beea.u.w = 0u;
        beeb.u.x = (quad == 0) ? eelds[tb * 16 + lx] : 0u;
        beeb.u.y = 0u; beeb.u.z = 0u; beeb.u.w = 0u;

        f32x4 aa0 = {0,0,0,0}, ab0 = {0,0,0,0};
        aa0 = __builtin_amdgcn_mfma_f32_16x16x32_bf16(a[0].s, ba0.s, aa0, 0, 0, 0);
        ab0 = __builtin_amdgcn_mfma_f32_16x16x32_bf16(a[0].s, bb0.s, ab0, 0, 0, 0);
        aa0 = __builtin_amdgcn_mfma_f32_16x16x32_bf16(a[1].s, ba1.s, aa0, 0, 0, 0);
        ab0 = __builtin_amdgcn_mfma_f32_16x16x32_bf16(a[1].s, bb1.s, ab0, 0, 0, 0);
        aa0 = __builtin_amdgcn_mfma_f32_16x16x32_bf16(aee.s, beea.s, aa0, 0, 0, 0);
        ab0 = __builtin_amdgcn_mfma_f32_16x16x32_bf16(aee.s, beeb.s, ab0, 0, 0, 0);

        unsigned cba = (unsigned)(ta * 16 + lx), cbb = (unsigned)(tb * 16 + lx);
#pragma unroll
        for (int r = 0; r < 4; ++r) {
            float ka0 = __uint_as_float((__float_as_uint(aa0[r]) & 0xFFFFFE00u) | cba);
            float kb0 = __uint_as_float((__float_as_uint(ab0[r]) & 0xFFFFFE00u) | cbb);
            best0[r] = fminf(fminf(best0[r], ka0), kb0);
        }
    }

    // ---- Cross-lane argmin (butterfly over low 4 lane bits) + SSE ----
    float lsse = zsq;
#pragma unroll
    for (int r = 0; r < 4; ++r) {
        float v = best0[r];
#pragma unroll
        for (int m = 1; m < 16; m <<= 1) v = fminf(v, __shfl_xor(v, m, 64));
        if (lx == 4 * quad + r) {   // one writer per (quad,r): row = 4*quad+r
            unsigned u = __float_as_uint(v);
            int c = (int)(u & 0x1FFu);
            bks[wave * 16 + 4 * quad + r] = c;
            atomicAdd(&hcnt[c], 1u);
            lsse += __uint_as_float(u & 0xFFFFFE00u);
        }
    }
#pragma unroll
    for (int off = 32; off > 0; off >>= 1) lsse += __shfl_down(lsse, off, 64);
    if (lane == 0) red[wave] = lsse;

    __syncthreads();   // bks + red + hcnt visible (full drain OK here)
    if (tid == 0) {
        float s = 0.f;
#pragma unroll
        for (int i = 0; i < 8; ++i) s += red[i];
        sse_arr[blockIdx.x] = s;
    }

    // ---- Epilogue: thread -> (pixel = tid&127, d-quarter = tid>>7) ----
    {
        int q = tid & (PPB - 1);
        int dq = tid >> 7;          // 0..3
        int bk = bks[q];
        const float4* Er = (const float4*)(E + (size_t)bk * D + dq * 16);
        float* ob = out + 1 + (size_t)b * (D * HW) + (size_t)dq * 16 * HW + s0 + q;
#pragma unroll
        for (int v4i = 0; v4i < 4; ++v4i) {
            float4 e4 = Er[v4i];
            ob[(size_t)(4 * v4i + 0) * HW] = e4.x;
            ob[(size_t)(4 * v4i + 1) * HW] = e4.y;
            ob[(size_t)(4 * v4i + 2) * HW] = e4.z;
            ob[(size_t)(4 * v4i + 3) * HW] = e4.w;
        }
    }

    // ---- flush histogram ----
    {
        unsigned hc = hcnt[tid];
        if (hc) atomicAdd(&counts[tid], hc);
    }

    // ---- fused finalize: last block computes loss + perplexity ----
    __syncthreads();
    if (tid == 0) {
        __threadfence();
        unsigned t = atomicAdd(ticket, 1u);
        sflag = (t == (unsigned)(NBLK - 1)) ? 1 : 0;
    }
    __syncthreads();
    if (sflag) {
        float cf = (float)atomicAdd(&counts[tid], 0u);
        float pa = cf / (float)NPIX + 1e-10f;
        float t = pa * logf(pa);
        float s = atomicAdd(&sse_arr[tid], 0.0f) + atomicAdd(&sse_arr[tid + 512], 0.0f);
#pragma unroll
        for (int off = 32; off > 0; off >>= 1) {
            t += __shfl_down(t, off, 64);
            s += __shfl_down(s, off, 64);
        }
        if (lane == 0) { red[wave] = t; red2[wave] = s; }
        __syncthreads();
        if (tid == 0) {
            float tot = 0.f, st = 0.f;
#pragma unroll
            for (int i = 0; i < 8; ++i) { tot += red[i]; st += red2[i]; }
            out[0] = (1.f + BETA) * st / (float)NELEM;
            out[out_size - 1] = expf(-tot);
        }
    }
}

extern "C" void kernel_launch(void* const* d_in, const int* in_sizes, int n_in,
                              void* d_out, int out_size, void* d_ws, size_t ws_size,
                              hipStream_t stream) {
    const float* z = (const float*)d_in[0];
    const float* E = (const float*)d_in[1];
    float* out = (float*)d_out;

    unsigned int* base = (unsigned int*)d_ws;
    unsigned int* ticket = base;                          // [0..3]
    unsigned int* counts = base + 4;                      // 512 uints
    float* sse_arr = (float*)(base + 4 + K);              // 1024 floats (per block)
    uint4* gsb = (uint4*)(base + 4 + K + NBLK);           // 64 KB B-frags (16-B aligned)
    unsigned int* eepk = base + 4 + K + NBLK + 4096 * 4;  // 512 uints

    hipMemsetAsync(d_ws, 0, (4 + K) * sizeof(unsigned int), stream);  // ticket + counts
    vq_prep<<<4, 128, 0, stream>>>(E, gsb, eepk);
    vq_main<<<NBLK, 512, 0, stream>>>(z, E, out, out_size, gsb, eepk,
                                      sse_arr, counts, ticket);
}

// Round 7
// 126.570 us; speedup vs baseline: 1.7712x; 1.1585x over previous
//
#include <hip/hip_runtime.h>
#include <math.h>

constexpr int K = 512;
constexpr int D = 64;
constexpr int HW = 64 * 64;                      // 4096
constexpr int NPIX = 131072;
constexpr long long NELEM = (long long)NPIX * D; // 8388608
constexpr float BETA = 0.25f;
constexpr int PPB = 128;                         // pixels per block (dist)
constexpr int NBLK = NPIX / PPB;                 // 1024 blocks

typedef __attribute__((ext_vector_type(8))) short short8;
typedef __attribute__((ext_vector_type(4))) float f32x4;

union frag_u { uint4 u; short8 s; };

__device__ inline unsigned short bf16rne(float x) {
    unsigned u = __float_as_uint(x);
    unsigned r = (u + 0x7FFFu + ((u >> 16) & 1u)) >> 16;
    return (unsigned short)r;
}

// truncated-bf16 pack: f0 -> low ushort, f1 -> high ushort (one v_perm_b32)
__device__ inline unsigned pk(float f0, float f1) {
    return __builtin_amdgcn_perm(__float_as_uint(f1), __float_as_uint(f0), 0x07060302u);
}

// ---- Prep: build bf16 B-frags (-2*E) + packed ||e||^2 hi/lo (verified R3-R6) ----
__global__ void vq_prep(const float* __restrict__ E,
                        uint4* __restrict__ gsb, unsigned* __restrict__ eepk) {
    const int n = blockIdx.x * 128 + threadIdx.x;   // 0..511
    const float4* er = (const float4*)(E + (size_t)n * D);
    const int tile = n >> 4, col = n & 15;
    float acc = 0.f;
#pragma unroll
    for (int g = 0; g < 8; ++g) {
        float4 c0 = er[2 * g], c1 = er[2 * g + 1];
        acc = fmaf(c0.x, c0.x, acc); acc = fmaf(c0.y, c0.y, acc);
        acc = fmaf(c0.z, c0.z, acc); acc = fmaf(c0.w, c0.w, acc);
        acc = fmaf(c1.x, c1.x, acc); acc = fmaf(c1.y, c1.y, acc);
        acc = fmaf(c1.z, c1.z, acc); acc = fmaf(c1.w, c1.w, acc);
        uint4 w;
        w.x = pk(-2.f * c0.x, -2.f * c0.y);
        w.y = pk(-2.f * c0.z, -2.f * c0.w);
        w.z = pk(-2.f * c1.x, -2.f * c1.y);
        w.w = pk(-2.f * c1.z, -2.f * c1.w);
        gsb[(tile * 2 + (g >> 2)) * 64 + ((g & 3) * 16 + col)] = w;
    }
    unsigned short eh = bf16rne(acc);
    unsigned short el = bf16rne(acc - __uint_as_float((unsigned)eh << 16));
    eepk[n] = (unsigned)eh | ((unsigned)el << 16);
}

// ---- Phase 1: coalesced z read -> LDS transpose -> frags -> ring-MFMA argmin.
// Emits u16 codes + per-block SSE + histogram. NO scattered global access.
__global__ __launch_bounds__(512, 6) void vq_dist(
    const float* __restrict__ z,
    const uint4* __restrict__ gsb, const unsigned* __restrict__ eepk,
    unsigned short* __restrict__ bks_g, float* __restrict__ sse_arr,
    unsigned int* __restrict__ counts) {

    __shared__ float zs[64 * 130];                      // 33.3 KB transpose buf
    __shared__ __align__(16) unsigned short sb[8192];   // 16 KB: 4-window B ring
    __shared__ __align__(16) unsigned int eelds[K];     // 2 KB packed ||e||^2
    __shared__ unsigned int hcnt[K];
    __shared__ float red[8];

    const int tid = threadIdx.x;
    const int wave = tid >> 6;      // 0..7 (wave = A-tile)
    const int lane = tid & 63;
    const int quad = lane >> 4;
    const int lx = lane & 15;

    const int p0 = blockIdx.x * PPB;
    const int b = p0 >> 12;
    const int s0 = p0 & (HW - 1);

    hcnt[tid] = 0u;

    // ---- DMA: eelds + ring windows 0,1 (issued first; drained by the barrier) ----
    __builtin_amdgcn_global_load_lds(
        (const __attribute__((address_space(1))) void*)(eepk + wave * 64 + lane),
        (__attribute__((address_space(3))) void*)((char*)eelds + wave * 256), 4, 0, 0);
    if (wave < 4) {
#pragma unroll
        for (int wn = 0; wn < 2; ++wn)
            __builtin_amdgcn_global_load_lds(
                (const __attribute__((address_space(1))) void*)
                    ((const char*)gsb + (size_t)(4 * wn + wave) * 1024 + lane * 16),
                (__attribute__((address_space(3))) void*)
                    ((char*)sb + wn * 4096 + wave * 1024), 16, 0, 0);
    }

    // ---- z stage: fully coalesced float4 reads -> zs[d][px] (stride 130) ----
    const float* zb = z + (size_t)b * (D * HW) + s0;
#pragma unroll
    for (int i = 0; i < 4; ++i) {
        int idx = i * 512 + tid;            // 0..2047
        int d = idx >> 5, c4 = idx & 31;    // d-row, float4 slot in 128-px row
        float4 v = *(const float4*)(zb + (size_t)d * HW + c4 * 4);
        float2* q2 = (float2*)&zs[d * 130 + c4 * 4];
        q2[0] = make_float2(v.x, v.y);
        q2[1] = make_float2(v.z, v.w);
    }

    __syncthreads();   // zs visible; drains ALL vmem (incl. DMAs) -> eelds/win0/1 ready

    // ---- pack A-frags from LDS (wave w = pixels w*16..w*16+15) + zsq partial ----
    frag_u a[2];
    float zsq = 0.f;
    const int pxi = wave * 16 + lx;
#pragma unroll
    for (int c = 0; c < 2; ++c) {
        float t0 = zs[(c * 32 + quad * 8 + 0) * 130 + pxi];
        float t1 = zs[(c * 32 + quad * 8 + 1) * 130 + pxi];
        float t2 = zs[(c * 32 + quad * 8 + 2) * 130 + pxi];
        float t3 = zs[(c * 32 + quad * 8 + 3) * 130 + pxi];
        float t4 = zs[(c * 32 + quad * 8 + 4) * 130 + pxi];
        float t5 = zs[(c * 32 + quad * 8 + 5) * 130 + pxi];
        float t6 = zs[(c * 32 + quad * 8 + 6) * 130 + pxi];
        float t7 = zs[(c * 32 + quad * 8 + 7) * 130 + pxi];
        zsq = fmaf(t0, t0, zsq); zsq = fmaf(t1, t1, zsq);
        zsq = fmaf(t2, t2, zsq); zsq = fmaf(t3, t3, zsq);
        zsq = fmaf(t4, t4, zsq); zsq = fmaf(t5, t5, zsq);
        zsq = fmaf(t6, t6, zsq); zsq = fmaf(t7, t7, zsq);
        a[c].u.x = pk(t0, t1); a[c].u.y = pk(t2, t3);
        a[c].u.z = pk(t4, t5); a[c].u.w = pk(t6, t7);
    }

    frag_u aee;
    aee.u.x = (quad == 0) ? 0x3F803F80u : 0u;
    aee.u.y = 0u; aee.u.z = 0u; aee.u.w = 0u;

    float best0[4];
#pragma unroll
    for (int r = 0; r < 4; ++r) best0[r] = __uint_as_float(0x7F800000u);

    // ---- Main loop: 16 iters, 4-window ring, depth-2 prefetch (R6-verified) ----
#pragma unroll 1
    for (int t2 = 0; t2 < 16; ++t2) {
        const int tn = (t2 + 2) & 15;
        if (wave < 4)
            __builtin_amdgcn_global_load_lds(
                (const __attribute__((address_space(1))) void*)
                    ((const char*)gsb + (size_t)(4 * tn + wave) * 1024 + lane * 16),
                (__attribute__((address_space(3))) void*)
                    ((char*)sb + (tn & 3) * 4096 + wave * 1024), 16, 0, 0);

        asm volatile("s_waitcnt vmcnt(2)" ::: "memory");
        __builtin_amdgcn_s_barrier();
        __builtin_amdgcn_sched_barrier(0);

        const int bi = (t2 & 3) * 2048;
        frag_u ba0, ba1, bb0, bb1;
        ba0.u = *(const uint4*)&sb[bi + 0 * 512 + lane * 8];
        ba1.u = *(const uint4*)&sb[bi + 1 * 512 + lane * 8];
        bb0.u = *(const uint4*)&sb[bi + 2 * 512 + lane * 8];
        bb1.u = *(const uint4*)&sb[bi + 3 * 512 + lane * 8];
        const int ta = 2 * t2, tb = 2 * t2 + 1;
        frag_u beea, beeb;
        beea.u.x = (quad == 0) ? eelds[ta * 16 + lx] : 0u;
        beea.u.y = 0u; beea.u.z = 0u; beea.u.w = 0u;
        beeb.u.x = (quad == 0) ? eelds[tb * 16 + lx] : 0u;
        beeb.u.y = 0u; beeb.u.z = 0u; beeb.u.w = 0u;

        f32x4 aa0 = {0,0,0,0}, ab0 = {0,0,0,0};
        aa0 = __builtin_amdgcn_mfma_f32_16x16x32_bf16(a[0].s, ba0.s, aa0, 0, 0, 0);
        ab0 = __builtin_amdgcn_mfma_f32_16x16x32_bf16(a[0].s, bb0.s, ab0, 0, 0, 0);
        aa0 = __builtin_amdgcn_mfma_f32_16x16x32_bf16(a[1].s, ba1.s, aa0, 0, 0, 0);
        ab0 = __builtin_amdgcn_mfma_f32_16x16x32_bf16(a[1].s, bb1.s, ab0, 0, 0, 0);
        aa0 = __builtin_amdgcn_mfma_f32_16x16x32_bf16(aee.s, beea.s, aa0, 0, 0, 0);
        ab0 = __builtin_amdgcn_mfma_f32_16x16x32_bf16(aee.s, beeb.s, ab0, 0, 0, 0);

        unsigned cba = (unsigned)(ta * 16 + lx), cbb = (unsigned)(tb * 16 + lx);
#pragma unroll
        for (int r = 0; r < 4; ++r) {
            float ka0 = __uint_as_float((__float_as_uint(aa0[r]) & 0xFFFFFE00u) | cba);
            float kb0 = __uint_as_float((__float_as_uint(ab0[r]) & 0xFFFFFE00u) | cbb);
            best0[r] = fminf(fminf(best0[r], ka0), kb0);
        }
    }

    // ---- Cross-lane argmin + SSE + code emit (u16, tiny traffic) ----
    float lsse = zsq;
#pragma unroll
    for (int r = 0; r < 4; ++r) {
        float v = best0[r];
#pragma unroll
        for (int m = 1; m < 16; m <<= 1) v = fminf(v, __shfl_xor(v, m, 64));
        if (lx == 4 * quad + r) {
            unsigned u = __float_as_uint(v);
            int c = (int)(u & 0x1FFu);
            bks_g[p0 + wave * 16 + 4 * quad + r] = (unsigned short)c;
            atomicAdd(&hcnt[c], 1u);
            lsse += __uint_as_float(u & 0xFFFFFE00u);
        }
    }
#pragma unroll
    for (int off = 32; off > 0; off >>= 1) lsse += __shfl_down(lsse, off, 64);
    if (lane == 0) red[wave] = lsse;

    __syncthreads();
    if (tid == 0) {
        float s = 0.f;
#pragma unroll
        for (int i = 0; i < 8; ++i) s += red[i];
        sse_arr[blockIdx.x] = s;
    }
    unsigned hc = hcnt[tid];
    if (hc) atomicAdd(&counts[tid], hc);
}

// ---- Phase 2: E^T + codes staged in LDS -> fully coalesced z_q writes.
// Block 0 also computes loss + perplexity (stream order => vq_dist done).
__global__ __launch_bounds__(256, 4) void vq_scat(
    const float* __restrict__ E, float* __restrict__ out, int out_size,
    const unsigned short* __restrict__ bks_g,
    const float* __restrict__ sse_arr, const unsigned int* __restrict__ counts) {

    __shared__ float ET[16 * 513];                 // 32.8 KB: E^T slice [d][k]
    __shared__ __align__(8) unsigned short bcode[1024];
    __shared__ float red[4], red2[4];

    const int tid = threadIdx.x;
    const int wave = tid >> 6;
    const int lane = tid & 63;
    const int bid = blockIdx.x;
    const int b = bid >> 4;
    const int d0 = ((bid >> 2) & 3) * 16;
    const int sr = (bid & 3) * 1024;

    if (bid == 0) {   // finalize: loss + perplexity
        float t = 0.f, s = 0.f;
#pragma unroll
        for (int i = 0; i < 2; ++i) {
            float cf = (float)counts[tid + 256 * i];
            float pa = cf / (float)NPIX + 1e-10f;
            t += pa * logf(pa);
        }
#pragma unroll
        for (int i = 0; i < 4; ++i) s += sse_arr[tid + 256 * i];
#pragma unroll
        for (int off = 32; off > 0; off >>= 1) {
            t += __shfl_down(t, off, 64);
            s += __shfl_down(s, off, 64);
        }
        if (lane == 0) { red[wave] = t; red2[wave] = s; }
        __syncthreads();
        if (tid == 0) {
            float tot = 0.f, st = 0.f;
#pragma unroll
            for (int i = 0; i < 4; ++i) { tot += red[i]; st += red2[i]; }
            out[0] = (1.f + BETA) * st / (float)NELEM;
            out[out_size - 1] = expf(-tot);
        }
        __syncthreads();
    }

    // ---- stage E^T (16 d-columns) + this block's 1024 codes ----
#pragma unroll
    for (int r2 = 0; r2 < 2; ++r2) {
        int k = tid + r2 * 256;
        const float4* er = (const float4*)(E + (size_t)k * D + d0);
        float4 e0 = er[0], e1 = er[1], e2 = er[2], e3 = er[3];
        ET[ 0 * 513 + k] = e0.x; ET[ 1 * 513 + k] = e0.y;
        ET[ 2 * 513 + k] = e0.z; ET[ 3 * 513 + k] = e0.w;
        ET[ 4 * 513 + k] = e1.x; ET[ 5 * 513 + k] = e1.y;
        ET[ 6 * 513 + k] = e1.z; ET[ 7 * 513 + k] = e1.w;
        ET[ 8 * 513 + k] = e2.x; ET[ 9 * 513 + k] = e2.y;
        ET[10 * 513 + k] = e2.z; ET[11 * 513 + k] = e2.w;
        ET[12 * 513 + k] = e3.x; ET[13 * 513 + k] = e3.y;
        ET[14 * 513 + k] = e3.z; ET[15 * 513 + k] = e3.w;
    }
    {
        uint2 cw = *(const uint2*)(bks_g + (size_t)b * HW + sr + tid * 4);
        *(uint2*)&bcode[tid * 4] = cw;
    }
    __syncthreads();

    // ---- coalesced scatter: wave owns 4 d-rows, streams 16 x 64-px chunks ----
    float* ob = out + 1 + (size_t)b * (D * HW) + sr;
#pragma unroll 4
    for (int i = 0; i < 64; ++i) {
        int pid = wave * 64 + i;          // 0..255
        int d = pid >> 4;                 // 0..15
        int ch = pid & 15;                // 0..15
        int px = ch * 64 + lane;
        int code = (int)bcode[px];
        ob[(size_t)(d0 + d) * HW + px] = ET[d * 513 + code];
    }
}

extern "C" void kernel_launch(void* const* d_in, const int* in_sizes, int n_in,
                              void* d_out, int out_size, void* d_ws, size_t ws_size,
                              hipStream_t stream) {
    const float* z = (const float*)d_in[0];
    const float* E = (const float*)d_in[1];
    float* out = (float*)d_out;

    unsigned int* base = (unsigned int*)d_ws;
    unsigned int* counts = base + 4;                        // 512 uints
    float* sse_arr = (float*)(base + 4 + K);                // 1024 floats
    uint4* gsb = (uint4*)(base + 1540);                     // 64 KB (byte 6160, 16-B aligned)
    unsigned int* eepk = base + 1540 + 4096 * 4;            // 512 uints
    unsigned short* bks_g = (unsigned short*)(base + 18436); // 256 KB codes

    hipMemsetAsync(d_ws, 0, (4 + K) * sizeof(unsigned int), stream);  // counts
    vq_prep<<<4, 128, 0, stream>>>(E, gsb, eepk);
    vq_dist<<<NBLK, 512, 0, stream>>>(z, gsb, eepk, bks_g, sse_arr, counts);
    vq_scat<<<512, 256, 0, stream>>>(E, out, out_size, bks_g, sse_arr, counts);
}

// Round 8
// 115.960 us; speedup vs baseline: 1.9333x; 1.0915x over previous
//
#include <hip/hip_runtime.h>
#include <math.h>

constexpr int K = 512;
constexpr int D = 64;
constexpr int HW = 64 * 64;                      // 4096
constexpr int NPIX = 131072;
constexpr long long NELEM = (long long)NPIX * D; // 8388608
constexpr float BETA = 0.25f;
constexpr int PPB = 128;                         // pixels per block (dist)
constexpr int NBLK = NPIX / PPB;                 // 1024 blocks

typedef __attribute__((ext_vector_type(8))) short short8;
typedef __attribute__((ext_vector_type(4))) float f32x4;

union frag_u { uint4 u; short8 s; };

__device__ inline unsigned short bf16rne(float x) {
    unsigned u = __float_as_uint(x);
    unsigned r = (u + 0x7FFFu + ((u >> 16) & 1u)) >> 16;
    return (unsigned short)r;
}

// truncated-bf16 pack: f0 -> low ushort, f1 -> high ushort (one v_perm_b32)
__device__ inline unsigned pk(float f0, float f1) {
    return __builtin_amdgcn_perm(__float_as_uint(f1), __float_as_uint(f0), 0x07060302u);
}

// ---- Prep: build bf16 B-frags (-2*E) + packed ||e||^2 hi/lo (verified R3-R7).
// Also zeroes counts (replaces the hipMemsetAsync dispatch).
__global__ void vq_prep(const float* __restrict__ E,
                        uint4* __restrict__ gsb, unsigned* __restrict__ eepk,
                        unsigned int* __restrict__ counts) {
    const int n = blockIdx.x * 128 + threadIdx.x;   // 0..511
    counts[n] = 0u;
    const float4* er = (const float4*)(E + (size_t)n * D);
    const int tile = n >> 4, col = n & 15;
    float acc = 0.f;
#pragma unroll
    for (int g = 0; g < 8; ++g) {
        float4 c0 = er[2 * g], c1 = er[2 * g + 1];
        acc = fmaf(c0.x, c0.x, acc); acc = fmaf(c0.y, c0.y, acc);
        acc = fmaf(c0.z, c0.z, acc); acc = fmaf(c0.w, c0.w, acc);
        acc = fmaf(c1.x, c1.x, acc); acc = fmaf(c1.y, c1.y, acc);
        acc = fmaf(c1.z, c1.z, acc); acc = fmaf(c1.w, c1.w, acc);
        uint4 w;
        w.x = pk(-2.f * c0.x, -2.f * c0.y);
        w.y = pk(-2.f * c0.z, -2.f * c0.w);
        w.z = pk(-2.f * c1.x, -2.f * c1.y);
        w.w = pk(-2.f * c1.z, -2.f * c1.w);
        gsb[(tile * 2 + (g >> 2)) * 64 + ((g & 3) * 16 + col)] = w;
    }
    unsigned short eh = bf16rne(acc);
    unsigned short el = bf16rne(acc - __uint_as_float((unsigned)eh << 16));
    eepk[n] = (unsigned)eh | ((unsigned)el << 16);
}

// ---- Phase 1: coalesced z read packed to bf16 pairs in LDS (16.9 KB) ->
// A-frags by plain LDS reads -> ring-MFMA argmin (R6-verified schedule).
// LDS ~37 KB -> 4 blocks/CU. Emits u16 codes + per-block SSE + histogram.
__global__ __launch_bounds__(512, 8) void vq_dist(
    const float* __restrict__ z,
    const uint4* __restrict__ gsb, const unsigned* __restrict__ eepk,
    unsigned short* __restrict__ bks_g, float* __restrict__ sse_arr,
    unsigned int* __restrict__ counts) {

    __shared__ __align__(16) unsigned int zs32[32 * 132]; // 16.9 KB bf16-pair A buf
    __shared__ __align__(16) unsigned short sb[8192];     // 16 KB: 4-window B ring
    __shared__ __align__(16) unsigned int eelds[K];       // 2 KB packed ||e||^2
    __shared__ unsigned int hcnt[K];
    __shared__ float red[8];

    const int tid = threadIdx.x;
    const int wave = tid >> 6;      // 0..7 (wave = A-tile)
    const int lane = tid & 63;
    const int quad = lane >> 4;
    const int lx = lane & 15;

    const int p0 = blockIdx.x * PPB;
    const int b = p0 >> 12;
    const int s0 = p0 & (HW - 1);

    hcnt[tid] = 0u;

    // ---- DMA: eelds + ring windows 0,1 (issued first; drained by the barrier) ----
    __builtin_amdgcn_global_load_lds(
        (const __attribute__((address_space(1))) void*)(eepk + wave * 64 + lane),
        (__attribute__((address_space(3))) void*)((char*)eelds + wave * 256), 4, 0, 0);
    if (wave < 4) {
#pragma unroll
        for (int wn = 0; wn < 2; ++wn)
            __builtin_amdgcn_global_load_lds(
                (const __attribute__((address_space(1))) void*)
                    ((const char*)gsb + (size_t)(4 * wn + wave) * 1024 + lane * 16),
                (__attribute__((address_space(3))) void*)
                    ((char*)sb + wn * 4096 + wave * 1024), 16, 0, 0);
    }

    // ---- z stage: coalesced float4 reads, pk to bf16 pairs -> zs32[dp][px];
    //      exact fp32 ||z||^2 partial computed here from raw values ----
    const float* zb = z + (size_t)b * (D * HW) + s0;
    float zsqp = 0.f;
#pragma unroll
    for (int i = 0; i < 2; ++i) {
        int idx = i * 512 + tid;            // 0..1023
        int dp = idx >> 5;                  // d-pair row 0..31
        int c4 = idx & 31;                  // float4 slot in 128-px row
        const float* r0 = zb + (size_t)(2 * dp) * HW + c4 * 4;
        float4 v0 = *(const float4*)r0;
        float4 v1 = *(const float4*)(r0 + HW);
        zsqp = fmaf(v0.x, v0.x, zsqp); zsqp = fmaf(v0.y, v0.y, zsqp);
        zsqp = fmaf(v0.z, v0.z, zsqp); zsqp = fmaf(v0.w, v0.w, zsqp);
        zsqp = fmaf(v1.x, v1.x, zsqp); zsqp = fmaf(v1.y, v1.y, zsqp);
        zsqp = fmaf(v1.z, v1.z, zsqp); zsqp = fmaf(v1.w, v1.w, zsqp);
        uint4 w;
        w.x = pk(v0.x, v1.x); w.y = pk(v0.y, v1.y);
        w.z = pk(v0.z, v1.z); w.w = pk(v0.w, v1.w);
        *(uint4*)&zs32[dp * 132 + c4 * 4] = w;    // 132 stride: 16B-aligned rows
    }

    __syncthreads();   // zs32 visible; drains ALL vmem -> eelds/win0/win1 ready

    // ---- A-frags: 8 plain LDS u32 reads (pairs already packed) ----
    frag_u a[2];
    const int pxi = wave * 16 + lx;
#pragma unroll
    for (int c = 0; c < 2; ++c) {
        const int bdp = c * 16 + quad * 4;
        a[c].u.x = zs32[(bdp + 0) * 132 + pxi];
        a[c].u.y = zs32[(bdp + 1) * 132 + pxi];
        a[c].u.z = zs32[(bdp + 2) * 132 + pxi];
        a[c].u.w = zs32[(bdp + 3) * 132 + pxi];
    }

    frag_u aee;
    aee.u.x = (quad == 0) ? 0x3F803F80u : 0u;
    aee.u.y = 0u; aee.u.z = 0u; aee.u.w = 0u;

    float best0[4];
#pragma unroll
    for (int r = 0; r < 4; ++r) best0[r] = __uint_as_float(0x7F800000u);

    // ---- Main loop: 16 iters, 4-window ring, depth-2 prefetch (R6-verified) ----
#pragma unroll 1
    for (int t2 = 0; t2 < 16; ++t2) {
        const int tn = (t2 + 2) & 15;
        if (wave < 4)
            __builtin_amdgcn_global_load_lds(
                (const __attribute__((address_space(1))) void*)
                    ((const char*)gsb + (size_t)(4 * tn + wave) * 1024 + lane * 16),
                (__attribute__((address_space(3))) void*)
                    ((char*)sb + (tn & 3) * 4096 + wave * 1024), 16, 0, 0);

        asm volatile("s_waitcnt vmcnt(2)" ::: "memory");
        __builtin_amdgcn_s_barrier();
        __builtin_amdgcn_sched_barrier(0);

        const int bi = (t2 & 3) * 2048;
        frag_u ba0, ba1, bb0, bb1;
        ba0.u = *(const uint4*)&sb[bi + 0 * 512 + lane * 8];
        ba1.u = *(const uint4*)&sb[bi + 1 * 512 + lane * 8];
        bb0.u = *(const uint4*)&sb[bi + 2 * 512 + lane * 8];
        bb1.u = *(const uint4*)&sb[bi + 3 * 512 + lane * 8];
        const int ta = 2 * t2, tb = 2 * t2 + 1;
        frag_u beea, beeb;
        beea.u.x = (quad == 0) ? eelds[ta * 16 + lx] : 0u;
        beea.u.y = 0u; beea.u.z = 0u; beea.u.w = 0u;
        beeb.u.x = (quad == 0) ? eelds[tb * 16 + lx] : 0u;
        beeb.u.y = 0u; beeb.u.z = 0u; beeb.u.w = 0u;

        f32x4 aa0 = {0,0,0,0}, ab0 = {0,0,0,0};
        aa0 = __builtin_amdgcn_mfma_f32_16x16x32_bf16(a[0].s, ba0.s, aa0, 0, 0, 0);
        ab0 = __builtin_amdgcn_mfma_f32_16x16x32_bf16(a[0].s, bb0.s, ab0, 0, 0, 0);
        aa0 = __builtin_amdgcn_mfma_f32_16x16x32_bf16(a[1].s, ba1.s, aa0, 0, 0, 0);
        ab0 = __builtin_amdgcn_mfma_f32_16x16x32_bf16(a[1].s, bb1.s, ab0, 0, 0, 0);
        aa0 = __builtin_amdgcn_mfma_f32_16x16x32_bf16(aee.s, beea.s, aa0, 0, 0, 0);
        ab0 = __builtin_amdgcn_mfma_f32_16x16x32_bf16(aee.s, beeb.s, ab0, 0, 0, 0);

        unsigned cba = (unsigned)(ta * 16 + lx), cbb = (unsigned)(tb * 16 + lx);
#pragma unroll
        for (int r = 0; r < 4; ++r) {
            float ka0 = __uint_as_float((__float_as_uint(aa0[r]) & 0xFFFFFE00u) | cba);
            float kb0 = __uint_as_float((__float_as_uint(ab0[r]) & 0xFFFFFE00u) | cbb);
            best0[r] = fminf(fminf(best0[r], ka0), kb0);
        }
    }

    // ---- Cross-lane argmin + SSE + code emit (u16, tiny traffic) ----
    float lsse = zsqp;
#pragma unroll
    for (int r = 0; r < 4; ++r) {
        float v = best0[r];
#pragma unroll
        for (int m = 1; m < 16; m <<= 1) v = fminf(v, __shfl_xor(v, m, 64));
        if (lx == 4 * quad + r) {
            unsigned u = __float_as_uint(v);
            int c = (int)(u & 0x1FFu);
            bks_g[p0 + wave * 16 + 4 * quad + r] = (unsigned short)c;
            atomicAdd(&hcnt[c], 1u);
            lsse += __uint_as_float(u & 0xFFFFFE00u);
        }
    }
#pragma unroll
    for (int off = 32; off > 0; off >>= 1) lsse += __shfl_down(lsse, off, 64);
    if (lane == 0) red[wave] = lsse;

    __syncthreads();
    if (tid == 0) {
        float s = 0.f;
#pragma unroll
        for (int i = 0; i < 8; ++i) s += red[i];
        sse_arr[blockIdx.x] = s;
    }
    unsigned hc = hcnt[tid];
    if (hc) atomicAdd(&counts[tid], hc);
}

// ---- Phase 2: E^T + codes staged in LDS -> coalesced z_q writes.
// 1024 blocks (2x R7) for more CU overlap; block 0 computes loss + perplexity.
__global__ __launch_bounds__(256, 4) void vq_scat(
    const float* __restrict__ E, float* __restrict__ out, int out_size,
    const unsigned short* __restrict__ bks_g,
    const float* __restrict__ sse_arr, const unsigned int* __restrict__ counts) {

    __shared__ float ET[16 * 513];                 // 32.8 KB: E^T slice [d][k]
    __shared__ __align__(4) unsigned short bcode[512];
    __shared__ float red[4], red2[4];

    const int tid = threadIdx.x;
    const int wave = tid >> 6;
    const int lane = tid & 63;
    const int bid = blockIdx.x;
    const int b = bid >> 5;              // 0..31
    const int d0 = ((bid >> 3) & 3) * 16;
    const int sr = (bid & 7) * 512;

    if (bid == 0) {   // finalize: loss + perplexity (stream order => dist done)
        float t = 0.f, s = 0.f;
#pragma unroll
        for (int i = 0; i < 2; ++i) {
            float cf = (float)counts[tid + 256 * i];
            float pa = cf / (float)NPIX + 1e-10f;
            t += pa * logf(pa);
        }
#pragma unroll
        for (int i = 0; i < 4; ++i) s += sse_arr[tid + 256 * i];
#pragma unroll
        for (int off = 32; off > 0; off >>= 1) {
            t += __shfl_down(t, off, 64);
            s += __shfl_down(s, off, 64);
        }
        if (lane == 0) { red[wave] = t; red2[wave] = s; }
        __syncthreads();
        if (tid == 0) {
            float tot = 0.f, st = 0.f;
#pragma unroll
            for (int i = 0; i < 4; ++i) { tot += red[i]; st += red2[i]; }
            out[0] = (1.f + BETA) * st / (float)NELEM;
            out[out_size - 1] = expf(-tot);
        }
        __syncthreads();
    }

    // ---- stage E^T (16 d-columns) + this block's 512 codes ----
#pragma unroll
    for (int r2 = 0; r2 < 2; ++r2) {
        int k = tid + r2 * 256;
        const float4* er = (const float4*)(E + (size_t)k * D + d0);
        float4 e0 = er[0], e1 = er[1], e2 = er[2], e3 = er[3];
        ET[ 0 * 513 + k] = e0.x; ET[ 1 * 513 + k] = e0.y;
        ET[ 2 * 513 + k] = e0.z; ET[ 3 * 513 + k] = e0.w;
        ET[ 4 * 513 + k] = e1.x; ET[ 5 * 513 + k] = e1.y;
        ET[ 6 * 513 + k] = e1.z; ET[ 7 * 513 + k] = e1.w;
        ET[ 8 * 513 + k] = e2.x; ET[ 9 * 513 + k] = e2.y;
        ET[10 * 513 + k] = e2.z; ET[11 * 513 + k] = e2.w;
        ET[12 * 513 + k] = e3.x; ET[13 * 513 + k] = e3.y;
        ET[14 * 513 + k] = e3.z; ET[15 * 513 + k] = e3.w;
    }
    {
        unsigned cw = *(const unsigned*)(bks_g + (size_t)b * HW + sr + tid * 2);
        *(unsigned*)&bcode[tid * 2] = cw;
    }
    __syncthreads();

    // ---- coalesced scatter: 32 iters/thread, 256 B per wave-instr ----
    float* ob = out + 1 + (size_t)b * (D * HW) + sr;
#pragma unroll 4
    for (int i = 0; i < 32; ++i) {
        int pid = wave * 32 + i;          // 0..127
        int d = pid >> 3;                 // 0..15
        int ch = pid & 7;                 // 0..7
        int px = ch * 64 + lane;          // 0..511
        int code = (int)bcode[px];
        ob[(size_t)(d0 + d) * HW + px] = ET[d * 513 + code];
    }
}

extern "C" void kernel_launch(void* const* d_in, const int* in_sizes, int n_in,
                              void* d_out, int out_size, void* d_ws, size_t ws_size,
                              hipStream_t stream) {
    const float* z = (const float*)d_in[0];
    const float* E = (const float*)d_in[1];
    float* out = (float*)d_out;

    unsigned int* base = (unsigned int*)d_ws;
    unsigned int* counts = base;                             // 512 uints
    float* sse_arr = (float*)(base + K);                     // 1024 floats
    uint4* gsb = (uint4*)(base + 1536);                      // 64 KB (byte 6144, 16-B aligned)
    unsigned int* eepk = base + 1536 + 4096 * 4;             // 512 uints
    unsigned short* bks_g = (unsigned short*)(base + 18432); // 256 KB codes

    vq_prep<<<4, 128, 0, stream>>>(E, gsb, eepk, counts);
    vq_dist<<<NBLK, 512, 0, stream>>>(z, gsb, eepk, bks_g, sse_arr, counts);
    vq_scat<<<1024, 256, 0, stream>>>(E, out, out_size, bks_g, sse_arr, counts);
}